// Round 1
// 306.953 us; speedup vs baseline: 1.0381x; 1.0381x over previous
//
#include <hip/hip_runtime.h>
#include <hip/hip_bf16.h>
#include <stdint.h>

#define D_IN   2048
#define D_SAE  32768
#define K_NNZ  64

#define SLICE_COLS 32
#define N_SLICES   (D_IN / SLICE_COLS)   // 64
#define N_XCD      8

typedef float vfloat4 __attribute__((ext_vector_type(4)));  // native vec for nontemporal
typedef int   vint4   __attribute__((ext_vector_type(4)));

static __device__ __forceinline__ uint16_t bf16_bits(float x) {
  __hip_bfloat16 h = __float2bfloat16(x);
  return *reinterpret_cast<uint16_t*>(&h);
}

// ---------------------------------------------------------------------------
// Dedup precompute: scatter .set = last-write-wins. v_clean[r][k] = 0 if any
// k' > k shares idx. One wave per row; runs once, removes dedup from the
// slice loop entirely.
// ---------------------------------------------------------------------------
__global__ __launch_bounds__(64) void dedup_values(
    const int* __restrict__ indices, const float* __restrict__ values,
    float* __restrict__ v_clean) {
  __shared__ int si[K_NNZ];
  const int r = blockIdx.x;
  const int k = threadIdx.x;
  const int my = indices[(size_t)r * K_NNZ + k];
  si[k] = my;
  __syncthreads();
  float v = values[(size_t)r * K_NNZ + k];
  for (int k2 = k + 1; k2 < K_NNZ; ++k2) {
    if (si[k2] == my) { v = 0.0f; break; }
  }
  v_clean[(size_t)r * K_NNZ + k] = v;
}

// ---------------------------------------------------------------------------
// Transpose: W (2048 x 32768) fp32 -> WT bf16. Tile 64(d) x 256(s); reads are
// full 1KB contiguous spans per W row, LDS XOR-swizzled chunk layout
// (phase-A b128 writes capacity-optimal, phase-B scalar reads <=2-way banked).
//
// v2b (main path): SLICE-BLOCKED output layout
//     WT_b[slice][row][cw],  slice = col/32, cw = col%32
// so each 32-col slice is a CONTIGUOUS 2MB region (half an XCD L2, no cache
// line straddles two slices -> each slice fetched from HBM exactly once by
// exactly one XCD during decode).
// ---------------------------------------------------------------------------
#define TP_D 64
#define TP_S 256

static __device__ __forceinline__ int sw_idx(int r, int c) {
  return (((c >> 2) ^ ((r >> 3) & 7)) << 2) + (c & 3);
}

__global__ __launch_bounds__(256) void transpose_to_bf16_v2b(
    const float* __restrict__ W, __hip_bfloat16* __restrict__ WT) {
  __shared__ float tile[TP_D][TP_S];
  const int s0 = blockIdx.x * TP_S;
  const int d0 = blockIdx.y * TP_D;
  const int tid = threadIdx.x;
  const int w = tid >> 6, l = tid & 63;

  // Phase A: wave w loads rows w*16..w*16+15; per row one 1KB wave-load.
#pragma unroll
  for (int i = 0; i < 16; ++i) {
    const int r = w * 16 + i;
    const float4 v = *reinterpret_cast<const float4*>(
        &W[(size_t)(d0 + r) * D_SAE + s0 + l * 4]);
    const int p = l ^ ((r >> 3) & 7);   // chunk swizzle
    *reinterpret_cast<float4*>(&tile[r][p << 2]) = v;
  }
  __syncthreads();

  // Phase B: wave w covers s_local [w*64, w*64+64); lane: a=d-chunk, sub=s.
  const int a = l & 7;
  const int sub = l >> 3;
#pragma unroll
  for (int i = 0; i < 8; ++i) {
    const int sl = w * 64 + i * 8 + sub;
    uint32_t u[4];
#pragma unroll
    for (int jj = 0; jj < 4; ++jj) {
      const float f0 = tile[a * 8 + 2 * jj][sw_idx(a * 8 + 2 * jj, sl)];
      const float f1 = tile[a * 8 + 2 * jj + 1][sw_idx(a * 8 + 2 * jj + 1, sl)];
      u[jj] = (uint32_t)bf16_bits(f0) | ((uint32_t)bf16_bits(f1) << 16);
    }
    const int d = d0 + a * 8;            // global col of this 8-col chunk
    const int slice = d >> 5;            // 32-col slice id
    const int cw = d & 31;               // col within slice (0,8,16,24)
    *reinterpret_cast<uint4*>(
        &WT[((size_t)slice * D_SAE + (size_t)(s0 + sl)) * SLICE_COLS + cw]) =
        *reinterpret_cast<uint4*>(u);
  }
}

// Row-major variant kept for the fallback decode path.
__global__ __launch_bounds__(256) void transpose_to_bf16_v2(
    const float* __restrict__ W, __hip_bfloat16* __restrict__ WT) {
  __shared__ float tile[TP_D][TP_S];
  const int s0 = blockIdx.x * TP_S;
  const int d0 = blockIdx.y * TP_D;
  const int tid = threadIdx.x;
  const int w = tid >> 6, l = tid & 63;
#pragma unroll
  for (int i = 0; i < 16; ++i) {
    const int r = w * 16 + i;
    const float4 v = *reinterpret_cast<const float4*>(
        &W[(size_t)(d0 + r) * D_SAE + s0 + l * 4]);
    const int p = l ^ ((r >> 3) & 7);
    *reinterpret_cast<float4*>(&tile[r][p << 2]) = v;
  }
  __syncthreads();
  const int a = l & 7;
  const int sub = l >> 3;
#pragma unroll
  for (int i = 0; i < 8; ++i) {
    const int sl = w * 64 + i * 8 + sub;
    uint32_t u[4];
#pragma unroll
    for (int jj = 0; jj < 4; ++jj) {
      const float f0 = tile[a * 8 + 2 * jj][sw_idx(a * 8 + 2 * jj, sl)];
      const float f1 = tile[a * 8 + 2 * jj + 1][sw_idx(a * 8 + 2 * jj + 1, sl)];
      u[jj] = (uint32_t)bf16_bits(f0) | ((uint32_t)bf16_bits(f1) << 16);
    }
    *reinterpret_cast<uint4*>(&WT[(size_t)(s0 + sl) * D_IN + d0 + a * 8]) =
        *reinterpret_cast<uint4*>(u);
  }
}

// ---------------------------------------------------------------------------
// Decode v4: 2MB slice-blocked L2 residency + 2-row pipelined gathers.
//   slice = 32 cols = 2MB contiguous chunk of WT_b = HALF an XCD L2, pinned
//   via blockIdx.x%8; y = phase (8 slices per XCD, sequential in dispatch
//   order). Even when two adjacent phases' blocks are co-resident on an XCD
//   (concurrency 160 > 128 per phase), 2+2MB still fits the 4MB L2 -> each
//   slice should be fetched from HBM ~once (vs 4.8x refetch of the 4MB-slice
//   scheme, FETCH_SIZE 640MB).
//   Staging loads are NONTEMPORAL so the 4MB/phase idx/val stream doesn't
//   evict the resident slice from L2.
//   Lane map: c=l&3 picks 16B chunk (8 cols), kg=l>>2 picks k; 4 gather steps
//   per row. Rows processed 2 at a time -> 8 independent dwordx4 gathers in
//   flight per wave iteration (VGPR headroom: prev kernel sat at 44 regs).
// ---------------------------------------------------------------------------
__global__ __launch_bounds__(256) void sae_decode_l2b(
    const int* __restrict__ indices, const float* __restrict__ v_clean,
    const __hip_bfloat16* __restrict__ WT, const float* __restrict__ bias,
    float* __restrict__ out) {
  const int m = blockIdx.x & 7;                  // XCD pin
  const int rowchunk = blockIdx.x >> 3;
  const int slice = blockIdx.y * N_XCD + m;      // 0..63, XCD = slice%8
  const int r0 = rowchunk * 64;
  const int tid = threadIdx.x;
  const int w = tid >> 6, l = tid & 63;

  __shared__ int   s_idx[64 * K_NNZ];
  __shared__ float s_val[64 * K_NNZ];

  {  // stage 64 rows of (idx, v_clean): nontemporal b128 loads (no L2 pollution)
    const vint4*   gi = reinterpret_cast<const vint4*>(&indices[(size_t)r0 * K_NNZ]);
    const vfloat4* gv = reinterpret_cast<const vfloat4*>(&v_clean[(size_t)r0 * K_NNZ]);
#pragma unroll
    for (int i = 0; i < 4; ++i) {
      const int e = i * 256 + tid;
      reinterpret_cast<vint4*>(s_idx)[e]   = __builtin_nontemporal_load(&gi[e]);
      reinterpret_cast<vfloat4*>(s_val)[e] = __builtin_nontemporal_load(&gv[e]);
    }
  }
  __syncthreads();

  const int kg = l >> 2;                 // k-group 0..15
  const int c  = l & 3;                  // 16B chunk 0..3
  const __hip_bfloat16* wbase =
      WT + (size_t)slice * ((size_t)D_SAE * SLICE_COLS) + c * 8;

  // bias is loop-invariant: hoist
  const int dbase = slice * SLICE_COLS + c * 8;
  const float4 b0 = *reinterpret_cast<const float4*>(&bias[dbase]);
  const float4 b1 = *reinterpret_cast<const float4*>(&bias[dbase + 4]);

  for (int i = 0; i < 16; i += 2) {
    const int rA = w + 4 * i;
    const int rB = rA + 4;
    float accA[8] = {0.f, 0.f, 0.f, 0.f, 0.f, 0.f, 0.f, 0.f};
    float accB[8] = {0.f, 0.f, 0.f, 0.f, 0.f, 0.f, 0.f, 0.f};
#pragma unroll
    for (int step = 0; step < 4; ++step) {
      const int k = step * 16 + kg;
      const int idxA = s_idx[rA * K_NNZ + k];   // broadcast across c -> no conflict
      const float vA = s_val[rA * K_NNZ + k];
      const int idxB = s_idx[rB * K_NNZ + k];
      const float vB = s_val[rB * K_NNZ + k];
      const uint4 wvA =
          *reinterpret_cast<const uint4*>(&wbase[(size_t)idxA * SLICE_COLS]);
      const uint4 wvB =
          *reinterpret_cast<const uint4*>(&wbase[(size_t)idxB * SLICE_COLS]);
#pragma unroll
      for (int j = 0; j < 4; ++j) {
        const uint32_t uA = (&wvA.x)[j];
        accA[2 * j + 0] = fmaf(vA, __uint_as_float(uA << 16), accA[2 * j + 0]);
        accA[2 * j + 1] = fmaf(vA, __uint_as_float(uA & 0xffff0000u), accA[2 * j + 1]);
        const uint32_t uB = (&wvB.x)[j];
        accB[2 * j + 0] = fmaf(vB, __uint_as_float(uB << 16), accB[2 * j + 0]);
        accB[2 * j + 1] = fmaf(vB, __uint_as_float(uB & 0xffff0000u), accB[2 * j + 1]);
      }
    }
#pragma unroll
    for (int j = 0; j < 8; ++j) {
      accA[j] += __shfl_xor(accA[j], 4, 64);
      accA[j] += __shfl_xor(accA[j], 8, 64);
      accA[j] += __shfl_xor(accA[j], 16, 64);
      accA[j] += __shfl_xor(accA[j], 32, 64);
      accB[j] += __shfl_xor(accB[j], 4, 64);
      accB[j] += __shfl_xor(accB[j], 8, 64);
      accB[j] += __shfl_xor(accB[j], 16, 64);
      accB[j] += __shfl_xor(accB[j], 32, 64);
    }
    if (kg == 0) {
      vfloat4 oA0 = {accA[0] + b0.x, accA[1] + b0.y, accA[2] + b0.z, accA[3] + b0.w};
      vfloat4 oA1 = {accA[4] + b1.x, accA[5] + b1.y, accA[6] + b1.z, accA[7] + b1.w};
      vfloat4* oA = reinterpret_cast<vfloat4*>(&out[(size_t)(r0 + rA) * D_IN + dbase]);
      __builtin_nontemporal_store(oA0, &oA[0]);
      __builtin_nontemporal_store(oA1, &oA[1]);
      vfloat4 oB0 = {accB[0] + b0.x, accB[1] + b0.y, accB[2] + b0.z, accB[3] + b0.w};
      vfloat4 oB1 = {accB[4] + b1.x, accB[5] + b1.y, accB[6] + b1.z, accB[7] + b1.w};
      vfloat4* oB = reinterpret_cast<vfloat4*>(&out[(size_t)(r0 + rB) * D_IN + dbase]);
      __builtin_nontemporal_store(oB0, &oB[0]);
      __builtin_nontemporal_store(oB1, &oB[1]);
    }
  }
}

// ---------------------------------------------------------------------------
// Fallback A (ws fits WT but not v_clean): R1's proven decode (in-kernel
// dedup, full-row blocks; uses row-major WT).
// ---------------------------------------------------------------------------
__global__ __launch_bounds__(256) void sae_decode_r1(
    const int* __restrict__ indices, const float* __restrict__ values,
    const __hip_bfloat16* __restrict__ WT, const float* __restrict__ bias,
    float* __restrict__ out) {
  const int row = blockIdx.x;
  const int tid = threadIdx.x;

  __shared__ int   s_idx[K_NNZ];
  __shared__ float s_val[K_NNZ];
  if (tid < K_NNZ) {
    s_idx[tid] = indices[(size_t)row * K_NNZ + tid];
    s_val[tid] = values[(size_t)row * K_NNZ + tid];
  }
  __syncthreads();
  if (tid < K_NNZ) {
    const int my = s_idx[tid];
    for (int k2 = tid + 1; k2 < K_NNZ; ++k2) {
      if (s_idx[k2] == my) { s_val[tid] = 0.0f; break; }
    }
  }
  __syncthreads();

  const int d0 = tid * 8;
  float acc[8];
  {
    const float4 b0 = *reinterpret_cast<const float4*>(&bias[d0]);
    const float4 b1 = *reinterpret_cast<const float4*>(&bias[d0 + 4]);
    acc[0] = b0.x; acc[1] = b0.y; acc[2] = b0.z; acc[3] = b0.w;
    acc[4] = b1.x; acc[5] = b1.y; acc[6] = b1.z; acc[7] = b1.w;
  }
#pragma unroll 4
  for (int k = 0; k < K_NNZ; ++k) {
    const float v = s_val[k];
    const int idx = s_idx[k];
    const uint4 wv = *reinterpret_cast<const uint4*>(
        &WT[(size_t)idx * D_IN + d0]);
#pragma unroll
    for (int j = 0; j < 4; ++j) {
      const uint32_t u = (&wv.x)[j];
      const float lo = __uint_as_float(u << 16);
      const float hi = __uint_as_float(u & 0xffff0000u);
      acc[2 * j + 0] = fmaf(v, lo, acc[2 * j + 0]);
      acc[2 * j + 1] = fmaf(v, hi, acc[2 * j + 1]);
    }
  }
  float4* o = reinterpret_cast<float4*>(&out[(size_t)row * D_IN + d0]);
  o[0] = make_float4(acc[0], acc[1], acc[2], acc[3]);
  o[1] = make_float4(acc[4], acc[5], acc[6], acc[7]);
}

// ---------------------------------------------------------------------------
// Fallback B (tiny ws): direct fp32 gather. Insurance only.
// ---------------------------------------------------------------------------
__global__ __launch_bounds__(256) void sae_decode_direct(
    const int* __restrict__ indices, const float* __restrict__ values,
    const float* __restrict__ W, const float* __restrict__ bias,
    float* __restrict__ out) {
  const int row = blockIdx.x;
  const int tid = threadIdx.x;
  __shared__ int   s_idx[K_NNZ];
  __shared__ float s_val[K_NNZ];
  if (tid < K_NNZ) {
    s_idx[tid] = indices[(size_t)row * K_NNZ + tid];
    s_val[tid] = values[(size_t)row * K_NNZ + tid];
  }
  __syncthreads();
  if (tid < K_NNZ) {
    const int my = s_idx[tid];
    for (int k2 = tid + 1; k2 < K_NNZ; ++k2) {
      if (s_idx[k2] == my) { s_val[tid] = 0.0f; break; }
    }
  }
  __syncthreads();
  const int d0 = tid * 8;
  float acc[8];
#pragma unroll
  for (int j = 0; j < 8; ++j) acc[j] = bias[d0 + j];
  for (int k = 0; k < K_NNZ; ++k) {
    const float v = s_val[k];
    const int idx = s_idx[k];
#pragma unroll
    for (int j = 0; j < 8; ++j) {
      acc[j] = fmaf(v, W[(size_t)(d0 + j) * D_SAE + idx], acc[j]);
    }
  }
  float4* o = reinterpret_cast<float4*>(&out[(size_t)row * D_IN + d0]);
  o[0] = make_float4(acc[0], acc[1], acc[2], acc[3]);
  o[1] = make_float4(acc[4], acc[5], acc[6], acc[7]);
}

extern "C" void kernel_launch(void* const* d_in, const int* in_sizes, int n_in,
                              void* d_out, int out_size, void* d_ws, size_t ws_size,
                              hipStream_t stream) {
  const int*   indices = (const int*)d_in[0];
  const float* values  = (const float*)d_in[1];
  const float* W       = (const float*)d_in[2];
  const float* bias    = (const float*)d_in[3];
  float* out = (float*)d_out;

  const int n_rows = in_sizes[0] / K_NNZ;  // 8192
  const size_t wt_bytes = (size_t)D_SAE * D_IN * sizeof(__hip_bfloat16);
  const size_t vc_bytes = (size_t)n_rows * K_NNZ * sizeof(float);

  if (ws_size >= wt_bytes + vc_bytes && (n_rows % 64) == 0) {
    __hip_bfloat16* WT = (__hip_bfloat16*)d_ws;   // slice-blocked layout
    float* v_clean = (float*)((char*)d_ws + wt_bytes);
    transpose_to_bf16_v2b<<<dim3(D_SAE / TP_S, D_IN / TP_D), 256, 0, stream>>>(W, WT);
    dedup_values<<<n_rows, 64, 0, stream>>>(indices, values, v_clean);
    dim3 g2(N_XCD * (n_rows / 64), N_SLICES / N_XCD);  // (1024, 8)
    sae_decode_l2b<<<g2, 256, 0, stream>>>(indices, v_clean, WT, bias, out);
  } else if (ws_size >= wt_bytes) {
    __hip_bfloat16* WT = (__hip_bfloat16*)d_ws;   // row-major layout
    transpose_to_bf16_v2<<<dim3(D_SAE / TP_S, D_IN / TP_D), 256, 0, stream>>>(W, WT);
    sae_decode_r1<<<n_rows, 256, 0, stream>>>(indices, values, WT, bias, out);
  } else {
    sae_decode_direct<<<n_rows, 256, 0, stream>>>(indices, values, W, bias, out);
  }
}

// Round 2
// 289.685 us; speedup vs baseline: 1.1000x; 1.0596x over previous
//
#include <hip/hip_runtime.h>
#include <hip/hip_bf16.h>
#include <stdint.h>

#define D_IN   2048
#define D_SAE  32768
#define K_NNZ  64

#define SLICE_COLS 32
#define N_SLICES   (D_IN / SLICE_COLS)   // 64
#define N_XCD      8
#define ROWS_PER_BLOCK 64

typedef float vfloat4 __attribute__((ext_vector_type(4)));  // native vec for nontemporal
typedef int   vint4   __attribute__((ext_vector_type(4)));

static __device__ __forceinline__ uint16_t bf16_bits(float x) {
  __hip_bfloat16 h = __float2bfloat16(x);
  return *reinterpret_cast<uint16_t*>(&h);
}

// ---------------------------------------------------------------------------
// Dedup + pack precompute: scatter .set = last-write-wins. Emits a PACKED
// (idx, val_bits) int2 array so the decode kernel stages ONE array and reads
// each (idx,val) pair with a single ds_read_b64.  piv[r*64 + k] natural order:
// decode's lane (kg = l>>2) reads piv[r*64 + step*16 + kg] -> 16 distinct
// 8B addresses = banks {2kg, 2kg+1} = conflict-free broadcast across c-lanes.
// ---------------------------------------------------------------------------
__global__ __launch_bounds__(64) void dedup_pack(
    const int* __restrict__ indices, const float* __restrict__ values,
    int2* __restrict__ piv) {
  __shared__ int si[K_NNZ];
  const int r = blockIdx.x;
  const int k = threadIdx.x;
  const int my = indices[(size_t)r * K_NNZ + k];
  si[k] = my;
  __syncthreads();
  float v = values[(size_t)r * K_NNZ + k];
  for (int k2 = k + 1; k2 < K_NNZ; ++k2) {
    if (si[k2] == my) { v = 0.0f; break; }
  }
  piv[(size_t)r * K_NNZ + k] = make_int2(my, __float_as_int(v));
}

// ---------------------------------------------------------------------------
// Transpose: W (2048 x 32768) fp32 -> WT bf16. Tile 64(d) x 256(s); reads are
// full 1KB contiguous spans per W row, LDS XOR-swizzled chunk layout.
// v2b (main path): SLICE-BLOCKED output WT_b[slice][row][cw], slice=col/32.
// Each 32-col slice is a contiguous 2MB region (half an XCD L2).
// ---------------------------------------------------------------------------
#define TP_D 64
#define TP_S 256

static __device__ __forceinline__ int sw_idx(int r, int c) {
  return (((c >> 2) ^ ((r >> 3) & 7)) << 2) + (c & 3);
}

__global__ __launch_bounds__(256) void transpose_to_bf16_v2b(
    const float* __restrict__ W, __hip_bfloat16* __restrict__ WT) {
  __shared__ float tile[TP_D][TP_S];
  const int s0 = blockIdx.x * TP_S;
  const int d0 = blockIdx.y * TP_D;
  const int tid = threadIdx.x;
  const int w = tid >> 6, l = tid & 63;

#pragma unroll
  for (int i = 0; i < 16; ++i) {
    const int r = w * 16 + i;
    const float4 v = *reinterpret_cast<const float4*>(
        &W[(size_t)(d0 + r) * D_SAE + s0 + l * 4]);
    const int p = l ^ ((r >> 3) & 7);   // chunk swizzle
    *reinterpret_cast<float4*>(&tile[r][p << 2]) = v;
  }
  __syncthreads();

  const int a = l & 7;
  const int sub = l >> 3;
#pragma unroll
  for (int i = 0; i < 8; ++i) {
    const int sl = w * 64 + i * 8 + sub;
    uint32_t u[4];
#pragma unroll
    for (int jj = 0; jj < 4; ++jj) {
      const float f0 = tile[a * 8 + 2 * jj][sw_idx(a * 8 + 2 * jj, sl)];
      const float f1 = tile[a * 8 + 2 * jj + 1][sw_idx(a * 8 + 2 * jj + 1, sl)];
      u[jj] = (uint32_t)bf16_bits(f0) | ((uint32_t)bf16_bits(f1) << 16);
    }
    const int d = d0 + a * 8;            // global col of this 8-col chunk
    const int slice = d >> 5;            // 32-col slice id
    const int cw = d & 31;               // col within slice (0,8,16,24)
    *reinterpret_cast<uint4*>(
        &WT[((size_t)slice * D_SAE + (size_t)(s0 + sl)) * SLICE_COLS + cw]) =
        *reinterpret_cast<uint4*>(u);
  }
}

// Row-major variant kept for the fallback decode path.
__global__ __launch_bounds__(256) void transpose_to_bf16_v2(
    const float* __restrict__ W, __hip_bfloat16* __restrict__ WT) {
  __shared__ float tile[TP_D][TP_S];
  const int s0 = blockIdx.x * TP_S;
  const int d0 = blockIdx.y * TP_D;
  const int tid = threadIdx.x;
  const int w = tid >> 6, l = tid & 63;
#pragma unroll
  for (int i = 0; i < 16; ++i) {
    const int r = w * 16 + i;
    const float4 v = *reinterpret_cast<const float4*>(
        &W[(size_t)(d0 + r) * D_SAE + s0 + l * 4]);
    const int p = l ^ ((r >> 3) & 7);
    *reinterpret_cast<float4*>(&tile[r][p << 2]) = v;
  }
  __syncthreads();
  const int a = l & 7;
  const int sub = l >> 3;
#pragma unroll
  for (int i = 0; i < 8; ++i) {
    const int sl = w * 64 + i * 8 + sub;
    uint32_t u[4];
#pragma unroll
    for (int jj = 0; jj < 4; ++jj) {
      const float f0 = tile[a * 8 + 2 * jj][sw_idx(a * 8 + 2 * jj, sl)];
      const float f1 = tile[a * 8 + 2 * jj + 1][sw_idx(a * 8 + 2 * jj + 1, sl)];
      u[jj] = (uint32_t)bf16_bits(f0) | ((uint32_t)bf16_bits(f1) << 16);
    }
    *reinterpret_cast<uint4*>(&WT[(size_t)(s0 + sl) * D_IN + d0 + a * 8]) =
        *reinterpret_cast<uint4*>(u);
  }
}

// ---------------------------------------------------------------------------
// Decode v5: latency-oriented rewrite.  Same 2MB slice residency + dispatch
// geometry as v4 (FETCH was already near-ideal at 222MB); attacks the real
// bottleneck (unhidden L2 gather latency + 4-level full shuffle-reduce):
//   * 8 gathers (2 rows x 4 steps) issued as ONE group into named uint4 regs
//     before any FMA (prev VGPR=48 proved only ~2 were in flight).
//   * butterfly reduce-SCATTER: each level keeps half the accumulators ->
//     8 shfl + 8 add per row (vs 32+32), final value is 1 float/lane,
//     stored as a coalesced wave write (lanes 0..31).
//   * packed int2 (idx,val) LDS: one ds_read_b64 per (row,step), conflict-
//     free broadcast across the 4 c-lanes; staging traffic halved.
//   * __launch_bounds__(256,5): 102-VGPR budget, 5 blocks/CU (LDS 32KB),
//     20 waves/CU.
// Lane map: c = l&3 (16B chunk of the 64B row-slice), kg = l>>2 (k-group).
// ---------------------------------------------------------------------------
static __device__ __forceinline__ void consume8(float (&acc)[8], const uint4 wv,
                                                const float v) {
#pragma unroll
  for (int j = 0; j < 4; ++j) {
    const uint32_t u = (&wv.x)[j];
    acc[2 * j + 0] = fmaf(v, __uint_as_float(u << 16), acc[2 * j + 0]);
    acc[2 * j + 1] = fmaf(v, __uint_as_float(u & 0xffff0000u), acc[2 * j + 1]);
  }
}

static __device__ __forceinline__ float reduce_scatter32(float (&acc)[8],
                                                         const int rb0,
                                                         const int rb1,
                                                         const int rb2) {
  float t4[4];
#pragma unroll
  for (int j = 0; j < 4; ++j) {
    const float send = rb0 ? acc[j] : acc[j + 4];
    const float keep = rb0 ? acc[j + 4] : acc[j];
    t4[j] = keep + __shfl_xor(send, 4, 64);
  }
  float t2[2];
#pragma unroll
  for (int j = 0; j < 2; ++j) {
    const float send = rb1 ? t4[j] : t4[j + 2];
    const float keep = rb1 ? t4[j + 2] : t4[j];
    t2[j] = keep + __shfl_xor(send, 8, 64);
  }
  const float send = rb2 ? t2[0] : t2[1];
  const float keep = rb2 ? t2[1] : t2[0];
  const float t1 = keep + __shfl_xor(send, 16, 64);
  return t1 + __shfl_xor(t1, 32, 64);
}

__global__ __launch_bounds__(256, 5) void sae_decode_l5(
    const int2* __restrict__ piv, const __hip_bfloat16* __restrict__ WT,
    const float* __restrict__ bias, float* __restrict__ out) {
  const int m = blockIdx.x & 7;                  // XCD pin
  const int rowchunk = blockIdx.x >> 3;
  const int slice = blockIdx.y * N_XCD + m;      // 0..63
  const int col0 = slice * SLICE_COLS;
  const int r0 = rowchunk * ROWS_PER_BLOCK;
  const int tid = threadIdx.x;
  const int w = tid >> 6, l = tid & 63;

  __shared__ __align__(16) int2 s_iv[ROWS_PER_BLOCK * K_NNZ];   // 32 KB

  {  // stage 64 rows of packed (idx,val): nontemporal b128 (protect L2 slice)
    const vint4* g = reinterpret_cast<const vint4*>(piv + (size_t)r0 * K_NNZ);
    vint4* sdst = reinterpret_cast<vint4*>(s_iv);
#pragma unroll
    for (int i = 0; i < 8; ++i) {
      sdst[i * 256 + tid] = __builtin_nontemporal_load(&g[i * 256 + tid]);
    }
  }
  __syncthreads();

  const int c = l & 3;                   // 16B chunk 0..3
  const int kg = l >> 2;                 // k-group 0..15
  const __hip_bfloat16* wbase =
      WT + (size_t)slice * ((size_t)D_SAE * SLICE_COLS) + c * 8;

  const int rb0 = kg & 1, rb1 = (kg >> 1) & 1, rb2 = (kg >> 2) & 1;
  const int mycol = c * 8 + rb0 * 4 + rb1 * 2 + rb2;   // bijective over 32
  const float mybias = bias[col0 + mycol];

  for (int i = 0; i < 16; i += 2) {
    const int rA = w + 4 * i;
    const int rB = rA + 4;
    // --- LDS: 4 (idx,val) pairs per row, conflict-free broadcast reads ---
    const int2 a0 = s_iv[rA * K_NNZ + 0 * 16 + kg];
    const int2 a1 = s_iv[rA * K_NNZ + 1 * 16 + kg];
    const int2 a2 = s_iv[rA * K_NNZ + 2 * 16 + kg];
    const int2 a3 = s_iv[rA * K_NNZ + 3 * 16 + kg];
    const int2 e0 = s_iv[rB * K_NNZ + 0 * 16 + kg];
    const int2 e1 = s_iv[rB * K_NNZ + 1 * 16 + kg];
    const int2 e2 = s_iv[rB * K_NNZ + 2 * 16 + kg];
    const int2 e3 = s_iv[rB * K_NNZ + 3 * 16 + kg];
    // --- issue all 8 gathers before any consumption ---
    const uint4 wA0 = *reinterpret_cast<const uint4*>(&wbase[(size_t)a0.x * SLICE_COLS]);
    const uint4 wA1 = *reinterpret_cast<const uint4*>(&wbase[(size_t)a1.x * SLICE_COLS]);
    const uint4 wA2 = *reinterpret_cast<const uint4*>(&wbase[(size_t)a2.x * SLICE_COLS]);
    const uint4 wA3 = *reinterpret_cast<const uint4*>(&wbase[(size_t)a3.x * SLICE_COLS]);
    const uint4 wB0 = *reinterpret_cast<const uint4*>(&wbase[(size_t)e0.x * SLICE_COLS]);
    const uint4 wB1 = *reinterpret_cast<const uint4*>(&wbase[(size_t)e1.x * SLICE_COLS]);
    const uint4 wB2 = *reinterpret_cast<const uint4*>(&wbase[(size_t)e2.x * SLICE_COLS]);
    const uint4 wB3 = *reinterpret_cast<const uint4*>(&wbase[(size_t)e3.x * SLICE_COLS]);
    // --- consume ---
    float accA[8] = {0.f, 0.f, 0.f, 0.f, 0.f, 0.f, 0.f, 0.f};
    float accB[8] = {0.f, 0.f, 0.f, 0.f, 0.f, 0.f, 0.f, 0.f};
    consume8(accA, wA0, __int_as_float(a0.y));
    consume8(accA, wA1, __int_as_float(a1.y));
    consume8(accA, wA2, __int_as_float(a2.y));
    consume8(accA, wA3, __int_as_float(a3.y));
    consume8(accB, wB0, __int_as_float(e0.y));
    consume8(accB, wB1, __int_as_float(e1.y));
    consume8(accB, wB2, __int_as_float(e2.y));
    consume8(accB, wB3, __int_as_float(e3.y));
    // --- butterfly reduce-scatter (8 shfl + 8 add per row) ---
    const float sA = reduce_scatter32(accA, rb0, rb1, rb2);
    const float sB = reduce_scatter32(accB, rb0, rb1, rb2);
    if (l < 32) {
      __builtin_nontemporal_store(
          sA + mybias, &out[(size_t)(r0 + rA) * D_IN + col0 + mycol]);
      __builtin_nontemporal_store(
          sB + mybias, &out[(size_t)(r0 + rB) * D_IN + col0 + mycol]);
    }
  }
}

// ---------------------------------------------------------------------------
// Fallback A (ws fits WT only): R1's proven decode (in-kernel dedup,
// full-row blocks; uses row-major WT).
// ---------------------------------------------------------------------------
__global__ __launch_bounds__(256) void sae_decode_r1(
    const int* __restrict__ indices, const float* __restrict__ values,
    const __hip_bfloat16* __restrict__ WT, const float* __restrict__ bias,
    float* __restrict__ out) {
  const int row = blockIdx.x;
  const int tid = threadIdx.x;

  __shared__ int   s_idx[K_NNZ];
  __shared__ float s_val[K_NNZ];
  if (tid < K_NNZ) {
    s_idx[tid] = indices[(size_t)row * K_NNZ + tid];
    s_val[tid] = values[(size_t)row * K_NNZ + tid];
  }
  __syncthreads();
  if (tid < K_NNZ) {
    const int my = s_idx[tid];
    for (int k2 = tid + 1; k2 < K_NNZ; ++k2) {
      if (s_idx[k2] == my) { s_val[tid] = 0.0f; break; }
    }
  }
  __syncthreads();

  const int d0 = tid * 8;
  float acc[8];
  {
    const float4 b0 = *reinterpret_cast<const float4*>(&bias[d0]);
    const float4 b1 = *reinterpret_cast<const float4*>(&bias[d0 + 4]);
    acc[0] = b0.x; acc[1] = b0.y; acc[2] = b0.z; acc[3] = b0.w;
    acc[4] = b1.x; acc[5] = b1.y; acc[6] = b1.z; acc[7] = b1.w;
  }
#pragma unroll 4
  for (int k = 0; k < K_NNZ; ++k) {
    const float v = s_val[k];
    const int idx = s_idx[k];
    const uint4 wv = *reinterpret_cast<const uint4*>(
        &WT[(size_t)idx * D_IN + d0]);
#pragma unroll
    for (int j = 0; j < 4; ++j) {
      const uint32_t u = (&wv.x)[j];
      const float lo = __uint_as_float(u << 16);
      const float hi = __uint_as_float(u & 0xffff0000u);
      acc[2 * j + 0] = fmaf(v, lo, acc[2 * j + 0]);
      acc[2 * j + 1] = fmaf(v, hi, acc[2 * j + 1]);
    }
  }
  float4* o = reinterpret_cast<float4*>(&out[(size_t)row * D_IN + d0]);
  o[0] = make_float4(acc[0], acc[1], acc[2], acc[3]);
  o[1] = make_float4(acc[4], acc[5], acc[6], acc[7]);
}

// ---------------------------------------------------------------------------
// Fallback B (tiny ws): direct fp32 gather. Insurance only.
// ---------------------------------------------------------------------------
__global__ __launch_bounds__(256) void sae_decode_direct(
    const int* __restrict__ indices, const float* __restrict__ values,
    const float* __restrict__ W, const float* __restrict__ bias,
    float* __restrict__ out) {
  const int row = blockIdx.x;
  const int tid = threadIdx.x;
  __shared__ int   s_idx[K_NNZ];
  __shared__ float s_val[K_NNZ];
  if (tid < K_NNZ) {
    s_idx[tid] = indices[(size_t)row * K_NNZ + tid];
    s_val[tid] = values[(size_t)row * K_NNZ + tid];
  }
  __syncthreads();
  if (tid < K_NNZ) {
    const int my = s_idx[tid];
    for (int k2 = tid + 1; k2 < K_NNZ; ++k2) {
      if (s_idx[k2] == my) { s_val[tid] = 0.0f; break; }
    }
  }
  __syncthreads();
  const int d0 = tid * 8;
  float acc[8];
#pragma unroll
  for (int j = 0; j < 8; ++j) acc[j] = bias[d0 + j];
  for (int k = 0; k < K_NNZ; ++k) {
    const float v = s_val[k];
    const int idx = s_idx[k];
#pragma unroll
    for (int j = 0; j < 8; ++j) {
      acc[j] = fmaf(v, W[(size_t)(d0 + j) * D_SAE + idx], acc[j]);
    }
  }
  float4* o = reinterpret_cast<float4*>(&out[(size_t)row * D_IN + d0]);
  o[0] = make_float4(acc[0], acc[1], acc[2], acc[3]);
  o[1] = make_float4(acc[4], acc[5], acc[6], acc[7]);
}

extern "C" void kernel_launch(void* const* d_in, const int* in_sizes, int n_in,
                              void* d_out, int out_size, void* d_ws, size_t ws_size,
                              hipStream_t stream) {
  const int*   indices = (const int*)d_in[0];
  const float* values  = (const float*)d_in[1];
  const float* W       = (const float*)d_in[2];
  const float* bias    = (const float*)d_in[3];
  float* out = (float*)d_out;

  const int n_rows = in_sizes[0] / K_NNZ;  // 8192
  const size_t wt_bytes = (size_t)D_SAE * D_IN * sizeof(__hip_bfloat16);
  const size_t piv_bytes = (size_t)n_rows * K_NNZ * sizeof(int2);

  if (ws_size >= wt_bytes + piv_bytes && (n_rows % ROWS_PER_BLOCK) == 0) {
    __hip_bfloat16* WT = (__hip_bfloat16*)d_ws;   // slice-blocked layout
    int2* piv = (int2*)((char*)d_ws + wt_bytes);
    transpose_to_bf16_v2b<<<dim3(D_SAE / TP_S, D_IN / TP_D), 256, 0, stream>>>(W, WT);
    dedup_pack<<<n_rows, 64, 0, stream>>>(indices, values, piv);
    dim3 g2(N_XCD * (n_rows / ROWS_PER_BLOCK), N_SLICES / N_XCD);  // (1024, 8)
    sae_decode_l5<<<g2, 256, 0, stream>>>(piv, WT, bias, out);
  } else if (ws_size >= wt_bytes) {
    __hip_bfloat16* WT = (__hip_bfloat16*)d_ws;   // row-major layout
    transpose_to_bf16_v2<<<dim3(D_SAE / TP_S, D_IN / TP_D), 256, 0, stream>>>(W, WT);
    sae_decode_r1<<<n_rows, 256, 0, stream>>>(indices, values, WT, bias, out);
  } else {
    sae_decode_direct<<<n_rows, 256, 0, stream>>>(indices, values, W, bias, out);
  }
}